// Round 3
// baseline (537.633 us; speedup 1.0000x reference)
//
#include <hip/hip_runtime.h>
#include <hip/hip_bf16.h>

#define T_TOK 2048
#define H_DIM 2048
#define F_DIM 1408
#define N_EXP 8
#define BM 128
#define BN 64
#define BK 64

typedef float f32x4 __attribute__((ext_vector_type(4)));
typedef short s16x8 __attribute__((ext_vector_type(8)));

// swizzled LDS byte offset: rows are 128B (64 bf16); XOR bits[4:6] with row&7
#define LOFF(row, kbyte) (((row) << 7) + ((kbyte) ^ (((row) & 7) << 4)))

__device__ __forceinline__ int bf2i(__hip_bfloat162 h) {
  int r; __builtin_memcpy(&r, &h, 4); return r;
}

__device__ __forceinline__ int4 pack8(float4 a, float4 b) {
  int4 r;
  r.x = bf2i(__float22bfloat162_rn(float2{a.x, a.y}));
  r.y = bf2i(__float22bfloat162_rn(float2{a.z, a.w}));
  r.z = bf2i(__float22bfloat162_rn(float2{b.x, b.y}));
  r.w = bf2i(__float22bfloat162_rn(float2{b.z, b.w}));
  return r;
}

__device__ __forceinline__ unsigned short f2bf(float f) {
  __hip_bfloat16 h = __float2bfloat16(f);
  unsigned short r; __builtin_memcpy(&r, &h, 2); return r;
}

__device__ __forceinline__ f32x4 mfma16(s16x8 a, s16x8 b, f32x4 c) {
  return __builtin_amdgcn_mfma_f32_16x16x32_bf16(a, b, c, 0, 0, 0);
}

// ---------------- router (+ fused x->bf16 cast) ----------------
__global__ void router_kernel(const float* __restrict__ x, const float* __restrict__ gw,
                              float* __restrict__ logits, int* __restrict__ tk_idx,
                              float* __restrict__ tk_w, unsigned short* __restrict__ xb) {
  __shared__ float xs[H_DIM];
  __shared__ float lg[N_EXP];
  const int t = blockIdx.x;
  const int tid = threadIdx.x;
  const float4 xv = ((const float4*)(x + (size_t)t * H_DIM))[tid];
  ((float4*)xs)[tid] = xv;
  // fused cast: 4 floats -> 4 bf16 (8B)
  int2 cw;
  cw.x = bf2i(__float22bfloat162_rn(float2{xv.x, xv.y}));
  cw.y = bf2i(__float22bfloat162_rn(float2{xv.z, xv.w}));
  ((int2*)(xb + (size_t)t * H_DIM))[tid] = cw;
  __syncthreads();
  const int w = tid >> 6, l = tid & 63;
  const float* g = gw + w * H_DIM;
  float s = 0.f;
  for (int j = l; j < H_DIM; j += 64) s += xs[j] * g[j];
#pragma unroll
  for (int o = 32; o; o >>= 1) s += __shfl_down(s, o);
  if (l == 0) lg[w] = s;
  __syncthreads();
  if (tid == 0) {
    float mx = lg[0];
#pragma unroll
    for (int i = 1; i < N_EXP; i++) mx = fmaxf(mx, lg[i]);
    float p[N_EXP];
#pragma unroll
    for (int i = 0; i < N_EXP; i++) p[i] = __expf(lg[i] - mx);
    int i0 = 0;
#pragma unroll
    for (int i = 1; i < N_EXP; i++) if (p[i] > p[i0]) i0 = i;
    int i1 = (i0 == 0) ? 1 : 0;
#pragma unroll
    for (int i = 0; i < N_EXP; i++) if (i != i0 && p[i] > p[i1]) i1 = i;
    const float ww = p[i0] + p[i1];
    tk_idx[t * 2] = i0; tk_idx[t * 2 + 1] = i1;
    tk_w[t * 2] = p[i0] / ww; tk_w[t * 2 + 1] = p[i1] / ww;
#pragma unroll
    for (int i = 0; i < N_EXP; i++) logits[t * N_EXP + i] = lg[i];
  }
}

// ---------------- deterministic per-expert list build (1 block/expert) ----------------
__global__ void build_lists(const int* __restrict__ tk_idx, const float* __restrict__ tk_w,
                            int* __restrict__ counts, int* __restrict__ entries,
                            float* __restrict__ wlist) {
  const int e = blockIdx.x;
  const int l = threadIdx.x;
  int base = 0;
  for (int t0 = 0; t0 < T_TOK; t0 += 64) {
    const int t = t0 + l;
    int sel = -1; float w = 0.f;
    const int i0 = tk_idx[t * 2], i1 = tk_idx[t * 2 + 1];
    if (i0 == e) { sel = t * 2; w = tk_w[t * 2]; }
    else if (i1 == e) { sel = t * 2 + 1; w = tk_w[t * 2 + 1]; }
    const unsigned long long mask = __ballot(sel >= 0);
    const int pos = base + __popcll(mask & ((1ull << l) - 1ull));
    if (sel >= 0) { entries[e * T_TOK + pos] = sel; wlist[e * T_TOK + pos] = w; }
    base += __popcll(mask);
  }
  if (l == 0) counts[e] = base;
}

// ---------------- GEMM1: h = silu(x@w1^T) * (x@w3^T), bf16 out ----------------
// double-buffered, raw-barrier pipeline: loads for tile t+1 stay in flight
// (vmcnt) under tile t's MFMAs; only lgkmcnt is drained at the barrier.
#define G1_STEP(SA, SB1, SB3, KNEXT)                                          \
  {                                                                           \
    *(int4*)((SA) + offA0) = va0;                                             \
    *(int4*)((SA) + offA1) = va1;                                             \
    *(int4*)((SB1) + offB) = pack8(b10, b11);                                 \
    *(int4*)((SB3) + offB) = pack8(b30, b31);                                 \
    const int kn = (KNEXT);                                                   \
    va0 = *(const int4*)(pa0 + kn);                                           \
    va1 = *(const int4*)(pa1 + kn);                                           \
    b10 = *(const float4*)(pb1 + kn);                                         \
    b11 = *(const float4*)(pb1 + kn + 4);                                     \
    b30 = *(const float4*)(pb3 + kn);                                         \
    b31 = *(const float4*)(pb3 + kn + 4);                                     \
    asm volatile("s_waitcnt lgkmcnt(0)" ::: "memory");                        \
    __builtin_amdgcn_s_barrier();                                             \
    _Pragma("unroll")                                                         \
    for (int kk = 0; kk < 2; kk++) {                                          \
      const int kbyte = kk * 64 + kb;                                         \
      const s16x8 a0 = *(const s16x8*)((SA) + LOFF(rowA0, kbyte));            \
      const s16x8 a1 = *(const s16x8*)((SA) + LOFF(rowA1, kbyte));            \
      const s16x8 p0 = *(const s16x8*)((SB1) + LOFF(rowB0, kbyte));           \
      const s16x8 p1 = *(const s16x8*)((SB1) + LOFF(rowB1, kbyte));           \
      const s16x8 q0 = *(const s16x8*)((SB3) + LOFF(rowB0, kbyte));           \
      const s16x8 q1 = *(const s16x8*)((SB3) + LOFF(rowB1, kbyte));           \
      aG[0][0] = mfma16(a0, p0, aG[0][0]); aG[0][1] = mfma16(a0, p1, aG[0][1]); \
      aG[1][0] = mfma16(a1, p0, aG[1][0]); aG[1][1] = mfma16(a1, p1, aG[1][1]); \
      aU[0][0] = mfma16(a0, q0, aU[0][0]); aU[0][1] = mfma16(a0, q1, aU[0][1]); \
      aU[1][0] = mfma16(a1, q0, aU[1][0]); aU[1][1] = mfma16(a1, q1, aU[1][1]); \
    }                                                                         \
  }

__global__ __launch_bounds__(512)
void moe_gemm1(const float* __restrict__ w1, const float* __restrict__ w3,
               const unsigned short* __restrict__ xb,
               const int* __restrict__ counts, const int* __restrict__ entries,
               unsigned short* __restrict__ hb) {
  const int e = blockIdx.x >> 4;
  const int tm = blockIdx.x & 15;
  const int cnt = counts[e];
  const int m0 = tm * BM;
  if (m0 >= cnt) return;
  const int rem = cnt - m0;
  const int n0 = blockIdx.y * BN;

  __shared__ unsigned short sA[2][BM * BK];
  __shared__ unsigned short sB1[2][BN * BK];
  __shared__ unsigned short sB3[2][BN * BK];
  char* sA0c = (char*)sA[0]; char* sA1c = (char*)sA[1];
  char* sB10c = (char*)sB1[0]; char* sB11c = (char*)sB1[1];
  char* sB30c = (char*)sB3[0]; char* sB31c = (char*)sB3[1];

  const int tid = threadIdx.x;
  const int lane = tid & 63;
  const int wave = tid >> 6;
  const int wm = wave >> 1, wn = wave & 1;

  const int* elist = entries + e * T_TOK + m0;

  const int r0 = tid >> 3;
  const int gc = tid & 7;
  const int ra1 = r0 + 64;
  const int tok0 = elist[r0 < rem ? r0 : 0] >> 1;
  const int tok1 = elist[ra1 < rem ? ra1 : 0] >> 1;
  const unsigned short* pa0 = xb + (size_t)tok0 * H_DIM + gc * 8;
  const unsigned short* pa1 = xb + (size_t)tok1 * H_DIM + gc * 8;
  const float* pb1 = w1 + ((size_t)e * F_DIM + n0 + r0) * H_DIM + gc * 8;
  const float* pb3 = w3 + ((size_t)e * F_DIM + n0 + r0) * H_DIM + gc * 8;
  const int offA0 = LOFF(r0, gc * 16);
  const int offA1 = LOFF(ra1, gc * 16);
  const int offB = LOFF(r0, gc * 16);

  const int rowA0 = wm * 32 + (lane & 15);
  const int rowA1 = rowA0 + 16;
  const int rowB0 = wn * 32 + (lane & 15);
  const int rowB1 = rowB0 + 16;
  const int kb = (lane >> 4) * 16;

  const f32x4 zero = {0.f, 0.f, 0.f, 0.f};
  f32x4 aG[2][2], aU[2][2];
#pragma unroll
  for (int i = 0; i < 2; i++)
#pragma unroll
    for (int j = 0; j < 2; j++) { aG[i][j] = zero; aU[i][j] = zero; }

  // prologue: load k=0 tile into regs
  int4 va0 = *(const int4*)(pa0);
  int4 va1 = *(const int4*)(pa1);
  float4 b10 = *(const float4*)(pb1);
  float4 b11 = *(const float4*)(pb1 + 4);
  float4 b30 = *(const float4*)(pb3);
  float4 b31 = *(const float4*)(pb3 + 4);

  for (int k0 = 0; k0 < H_DIM; k0 += 2 * BK) {
    const int k1 = k0 + BK;
    const int k2 = (k0 + 2 * BK < H_DIM) ? (k0 + 2 * BK) : 0;
    G1_STEP(sA0c, sB10c, sB30c, k1);
    G1_STEP(sA1c, sB11c, sB31c, k2);
  }

  // epilogue: h = silu(g)*u -> bf16 scatter by entry row
#pragma unroll
  for (int i = 0; i < 2; i++) {
#pragma unroll
    for (int r = 0; r < 4; r++) {
      const int m = wm * 32 + i * 16 + ((lane >> 4) << 2) + r;
      if (m < rem) {
        const int entry = elist[m];
        unsigned short* hp = hb + (size_t)entry * F_DIM + n0 + wn * 32 + (lane & 15);
#pragma unroll
        for (int j = 0; j < 2; j++) {
          const float g = aG[i][j][r];
          const float u = aU[i][j][r];
          const float s = g / (1.f + __expf(-g)) * u;
          hp[j * 16] = f2bf(s);
        }
      }
    }
  }
}

// ---------------- GEMM2: y = h@w2^T, weighted atomic combine ----------------
#define G2_STEP(SA, SB, KNEXT)                                                \
  {                                                                           \
    *(int4*)((SA) + offA0) = va0;                                             \
    *(int4*)((SA) + offA1) = va1;                                             \
    *(int4*)((SB) + offB) = pack8(b0, b1);                                    \
    const int kn = (KNEXT);                                                   \
    va0 = *(const int4*)(pa0 + kn);                                           \
    va1 = *(const int4*)(pa1 + kn);                                           \
    b0 = *(const float4*)(pb + kn);                                           \
    b1 = *(const float4*)(pb + kn + 4);                                       \
    asm volatile("s_waitcnt lgkmcnt(0)" ::: "memory");                        \
    __builtin_amdgcn_s_barrier();                                             \
    _Pragma("unroll")                                                         \
    for (int kk = 0; kk < 2; kk++) {                                          \
      const int kbyte = kk * 64 + kb;                                         \
      const s16x8 a0 = *(const s16x8*)((SA) + LOFF(rowA0, kbyte));            \
      const s16x8 a1 = *(const s16x8*)((SA) + LOFF(rowA1, kbyte));            \
      const s16x8 f0 = *(const s16x8*)((SB) + LOFF(rowB0, kbyte));            \
      const s16x8 f1 = *(const s16x8*)((SB) + LOFF(rowB1, kbyte));            \
      ac[0][0] = mfma16(a0, f0, ac[0][0]); ac[0][1] = mfma16(a0, f1, ac[0][1]); \
      ac[1][0] = mfma16(a1, f0, ac[1][0]); ac[1][1] = mfma16(a1, f1, ac[1][1]); \
    }                                                                         \
  }

__global__ __launch_bounds__(512)
void moe_gemm2(const float* __restrict__ w2,
               const unsigned short* __restrict__ hb,
               const int* __restrict__ counts, const int* __restrict__ entries,
               const float* __restrict__ wlist,
               float* __restrict__ out) {
  const int e = blockIdx.x >> 4;
  const int tm = blockIdx.x & 15;
  const int cnt = counts[e];
  const int m0 = tm * BM;
  if (m0 >= cnt) return;
  const int rem = cnt - m0;
  const int n0 = blockIdx.y * BN;

  __shared__ unsigned short sA[2][BM * BK];
  __shared__ unsigned short sB[2][BN * BK];
  char* sA0c = (char*)sA[0]; char* sA1c = (char*)sA[1];
  char* sB0c = (char*)sB[0]; char* sB1c = (char*)sB[1];

  const int tid = threadIdx.x;
  const int lane = tid & 63;
  const int wave = tid >> 6;
  const int wm = wave >> 1, wn = wave & 1;

  const int* elist = entries + e * T_TOK + m0;
  const float* wl = wlist + e * T_TOK + m0;

  const int r0 = tid >> 3;
  const int gc = tid & 7;
  const int ra1 = r0 + 64;
  const int en0 = elist[r0 < rem ? r0 : 0];
  const int en1 = elist[ra1 < rem ? ra1 : 0];
  const unsigned short* pa0 = hb + (size_t)en0 * F_DIM + gc * 8;
  const unsigned short* pa1 = hb + (size_t)en1 * F_DIM + gc * 8;
  const float* pb = w2 + ((size_t)e * H_DIM + n0 + r0) * F_DIM + gc * 8;
  const int offA0 = LOFF(r0, gc * 16);
  const int offA1 = LOFF(ra1, gc * 16);
  const int offB = LOFF(r0, gc * 16);

  const int rowA0 = wm * 32 + (lane & 15);
  const int rowA1 = rowA0 + 16;
  const int rowB0 = wn * 32 + (lane & 15);
  const int rowB1 = rowB0 + 16;
  const int kb = (lane >> 4) * 16;

  const f32x4 zero = {0.f, 0.f, 0.f, 0.f};
  f32x4 ac[2][2];
#pragma unroll
  for (int i = 0; i < 2; i++)
#pragma unroll
    for (int j = 0; j < 2; j++) ac[i][j] = zero;

  int4 va0 = *(const int4*)(pa0);
  int4 va1 = *(const int4*)(pa1);
  float4 b0 = *(const float4*)(pb);
  float4 b1 = *(const float4*)(pb + 4);

  for (int k0 = 0; k0 < F_DIM; k0 += 2 * BK) {
    const int k1 = k0 + BK;
    const int k2 = (k0 + 2 * BK < F_DIM) ? (k0 + 2 * BK) : 0;
    G2_STEP(sA0c, sB0c, k1);
    G2_STEP(sA1c, sB1c, k2);
  }

#pragma unroll
  for (int i = 0; i < 2; i++) {
#pragma unroll
    for (int r = 0; r < 4; r++) {
      const int m = wm * 32 + i * 16 + ((lane >> 4) << 2) + r;
      if (m < rem) {
        const int entry = elist[m];
        const int t = entry >> 1;
        const float wgt = wl[m];
        float* op = out + (size_t)t * H_DIM + n0 + wn * 32 + (lane & 15);
#pragma unroll
        for (int j = 0; j < 2; j++) atomicAdd(op + j * 16, wgt * ac[i][j][r]);
      }
    }
  }
}

extern "C" void kernel_launch(void* const* d_in, const int* in_sizes, int n_in,
                              void* d_out, int out_size, void* d_ws, size_t ws_size,
                              hipStream_t stream) {
  const float* x  = (const float*)d_in[0];
  const float* gw = (const float*)d_in[1];
  const float* w1 = (const float*)d_in[2];
  const float* w3 = (const float*)d_in[3];
  const float* w2 = (const float*)d_in[4];
  float* out = (float*)d_out;
  float* logits = out + (size_t)T_TOK * H_DIM;

  char* ws = (char*)d_ws;
  size_t off = 0;
  unsigned short* xb = (unsigned short*)(ws + off); off += (size_t)T_TOK * H_DIM * 2;      // 8 MB
  unsigned short* hb = (unsigned short*)(ws + off); off += (size_t)T_TOK * 2 * F_DIM * 2;  // 11.5 MB
  int*   tk_idx = (int*)(ws + off);   off += (size_t)T_TOK * 2 * 4;
  float* tk_w   = (float*)(ws + off); off += (size_t)T_TOK * 2 * 4;
  int*   counts = (int*)(ws + off);   off += 256;
  int*   entries = (int*)(ws + off);  off += (size_t)N_EXP * T_TOK * 4;
  float* wlist  = (float*)(ws + off); off += (size_t)N_EXP * T_TOK * 4;

  (void)hipMemsetAsync(d_out, 0, (size_t)out_size * sizeof(float), stream);
  router_kernel<<<dim3(T_TOK), 512, 0, stream>>>(x, gw, logits, tk_idx, tk_w, xb);
  build_lists<<<dim3(N_EXP), 64, 0, stream>>>(tk_idx, tk_w, counts, entries, wlist);
  moe_gemm1<<<dim3(N_EXP * (T_TOK / BM), F_DIM / BN), 512, 0, stream>>>(w1, w3, xb, counts, entries, hb);
  moe_gemm2<<<dim3(N_EXP * (T_TOK / BM), H_DIM / BN), 512, 0, stream>>>(w2, hb, counts, entries, wlist, out);
}

// Round 4
// 238.492 us; speedup vs baseline: 2.2543x; 2.2543x over previous
//
#include <hip/hip_runtime.h>
#include <hip/hip_bf16.h>

#define T_TOK 2048
#define H_DIM 2048
#define F_DIM 1408
#define N_EXP 8
#define BM 128
#define BN 64
#define BK 64

// work-item grid: x = item slot (40 covers worst case sum ceil(cnt/128) <= 39)
#define NITEM 40
#define G1_NY (F_DIM / BN)   // 22
#define G2_NY (H_DIM / BN)   // 32
#define G1_CHUNK ((NITEM * G1_NY) / 8)  // 110
#define G2_CHUNK ((NITEM * G2_NY) / 8)  // 160

typedef float f32x4 __attribute__((ext_vector_type(4)));
typedef short s16x8 __attribute__((ext_vector_type(8)));

// swizzled LDS byte offset: rows are 128B (64 bf16); XOR bits[4:6] with row&7
#define LOFF(row, kbyte) (((row) << 7) + ((kbyte) ^ (((row) & 7) << 4)))

__device__ __forceinline__ int bf2i(__hip_bfloat162 h) {
  int r; __builtin_memcpy(&r, &h, 4); return r;
}

__device__ __forceinline__ int4 pack8(float4 a, float4 b) {
  int4 r;
  r.x = bf2i(__float22bfloat162_rn(float2{a.x, a.y}));
  r.y = bf2i(__float22bfloat162_rn(float2{a.z, a.w}));
  r.z = bf2i(__float22bfloat162_rn(float2{b.x, b.y}));
  r.w = bf2i(__float22bfloat162_rn(float2{b.z, b.w}));
  return r;
}

__device__ __forceinline__ unsigned short f2bf(float f) {
  __hip_bfloat16 h = __float2bfloat16(f);
  unsigned short r; __builtin_memcpy(&r, &h, 2); return r;
}

__device__ __forceinline__ f32x4 mfma16(s16x8 a, s16x8 b, f32x4 c) {
  return __builtin_amdgcn_mfma_f32_16x16x32_bf16(a, b, c, 0, 0, 0);
}

// ---------------- router (+ fused x->bf16 cast) ----------------
__global__ void router_kernel(const float* __restrict__ x, const float* __restrict__ gw,
                              float* __restrict__ logits, int* __restrict__ tk_idx,
                              float* __restrict__ tk_w, unsigned short* __restrict__ xb) {
  __shared__ float xs[H_DIM];
  __shared__ float lg[N_EXP];
  const int t = blockIdx.x;
  const int tid = threadIdx.x;
  const float4 xv = ((const float4*)(x + (size_t)t * H_DIM))[tid];
  ((float4*)xs)[tid] = xv;
  int2 cw;
  cw.x = bf2i(__float22bfloat162_rn(float2{xv.x, xv.y}));
  cw.y = bf2i(__float22bfloat162_rn(float2{xv.z, xv.w}));
  ((int2*)(xb + (size_t)t * H_DIM))[tid] = cw;
  __syncthreads();
  const int w = tid >> 6, l = tid & 63;
  const float* g = gw + w * H_DIM;
  float s = 0.f;
  for (int j = l; j < H_DIM; j += 64) s += xs[j] * g[j];
#pragma unroll
  for (int o = 32; o; o >>= 1) s += __shfl_down(s, o);
  if (l == 0) lg[w] = s;
  __syncthreads();
  if (tid == 0) {
    float mx = lg[0];
#pragma unroll
    for (int i = 1; i < N_EXP; i++) mx = fmaxf(mx, lg[i]);
    float p[N_EXP];
#pragma unroll
    for (int i = 0; i < N_EXP; i++) p[i] = __expf(lg[i] - mx);
    int i0 = 0;
#pragma unroll
    for (int i = 1; i < N_EXP; i++) if (p[i] > p[i0]) i0 = i;
    int i1 = (i0 == 0) ? 1 : 0;
#pragma unroll
    for (int i = 0; i < N_EXP; i++) if (i != i0 && p[i] > p[i1]) i1 = i;
    const float ww = p[i0] + p[i1];
    tk_idx[t * 2] = i0; tk_idx[t * 2 + 1] = i1;
    tk_w[t * 2] = p[i0] / ww; tk_w[t * 2 + 1] = p[i1] / ww;
#pragma unroll
    for (int i = 0; i < N_EXP; i++) logits[t * N_EXP + i] = lg[i];
  }
}

// ---------------- deterministic per-expert list build (1 block/expert) ----------------
__global__ void build_lists(const int* __restrict__ tk_idx, const float* __restrict__ tk_w,
                            int* __restrict__ counts, int* __restrict__ entries,
                            float* __restrict__ wlist) {
  const int e = blockIdx.x;
  const int l = threadIdx.x;
  int base = 0;
  for (int t0 = 0; t0 < T_TOK; t0 += 64) {
    const int t = t0 + l;
    int sel = -1; float w = 0.f;
    const int i0 = tk_idx[t * 2], i1 = tk_idx[t * 2 + 1];
    if (i0 == e) { sel = t * 2; w = tk_w[t * 2]; }
    else if (i1 == e) { sel = t * 2 + 1; w = tk_w[t * 2 + 1]; }
    const unsigned long long mask = __ballot(sel >= 0);
    const int pos = base + __popcll(mask & ((1ull << l) - 1ull));
    if (sel >= 0) { entries[e * T_TOK + pos] = sel; wlist[e * T_TOK + pos] = w; }
    base += __popcll(mask);
  }
  if (l == 0) counts[e] = base;
}

// ---------------- dense work-item table: items[0]=n, items[1+i]=(e<<16)|mtile ----------------
__global__ void build_items(const int* __restrict__ counts, int* __restrict__ items) {
  if (threadIdx.x == 0) {
    int n = 0;
#pragma unroll
    for (int e = 0; e < N_EXP; e++) {
      const int c = counts[e];
      for (int m0 = 0; m0 < c; m0 += BM) items[1 + n++] = (e << 16) | (m0 / BM);
    }
    items[0] = n;
  }
}

// ---------------- GEMM1: h = silu(x@w1^T) * (x@w3^T), bf16 out ----------------
// depth-2 register prefetch: reg set written to LDS was loaded 2 steps ago, so
// the compiler emits a counted vmcnt (other set's 6 loads stay in flight).
#define G1_STEP(SA, SB1, SB3, VA0, VA1, B10, B11, B30, B31, KNEXT)            \
  {                                                                           \
    *(int4*)((SA) + offA0) = VA0;                                             \
    *(int4*)((SA) + offA1) = VA1;                                             \
    *(int4*)((SB1) + offB) = pack8(B10, B11);                                 \
    *(int4*)((SB3) + offB) = pack8(B30, B31);                                 \
    const int kn = (KNEXT);                                                   \
    VA0 = *(const int4*)(pa0 + kn);                                           \
    VA1 = *(const int4*)(pa1 + kn);                                           \
    B10 = *(const float4*)(pb1 + kn);                                         \
    B11 = *(const float4*)(pb1 + kn + 4);                                     \
    B30 = *(const float4*)(pb3 + kn);                                         \
    B31 = *(const float4*)(pb3 + kn + 4);                                     \
    asm volatile("s_waitcnt lgkmcnt(0)" ::: "memory");                        \
    __builtin_amdgcn_s_barrier();                                             \
    _Pragma("unroll")                                                         \
    for (int kk = 0; kk < 2; kk++) {                                          \
      const int kbyte = kk * 64 + kb;                                         \
      const s16x8 a0 = *(const s16x8*)((SA) + LOFF(rowA0, kbyte));            \
      const s16x8 a1 = *(const s16x8*)((SA) + LOFF(rowA1, kbyte));            \
      const s16x8 p0 = *(const s16x8*)((SB1) + LOFF(rowB0, kbyte));           \
      const s16x8 p1 = *(const s16x8*)((SB1) + LOFF(rowB1, kbyte));           \
      const s16x8 q0 = *(const s16x8*)((SB3) + LOFF(rowB0, kbyte));           \
      const s16x8 q1 = *(const s16x8*)((SB3) + LOFF(rowB1, kbyte));           \
      aG[0][0] = mfma16(a0, p0, aG[0][0]); aG[0][1] = mfma16(a0, p1, aG[0][1]); \
      aG[1][0] = mfma16(a1, p0, aG[1][0]); aG[1][1] = mfma16(a1, p1, aG[1][1]); \
      aU[0][0] = mfma16(a0, q0, aU[0][0]); aU[0][1] = mfma16(a0, q1, aU[0][1]); \
      aU[1][0] = mfma16(a1, q0, aU[1][0]); aU[1][1] = mfma16(a1, q1, aU[1][1]); \
    }                                                                         \
  }

__global__ __launch_bounds__(512)
void moe_gemm1(const float* __restrict__ w1, const float* __restrict__ w3,
               const unsigned short* __restrict__ xb,
               const int* __restrict__ counts, const int* __restrict__ entries,
               const int* __restrict__ items,
               unsigned short* __restrict__ hb) {
  // XCD-chunked bijective swizzle: 880 = 8 * 110
  const int lin = blockIdx.x;
  const int virt = (lin & 7) * G1_CHUNK + (lin >> 3);
  const int ix = virt % NITEM;
  const int iy = virt / NITEM;
  if (ix >= items[0]) return;
  const int it = items[1 + ix];
  const int e = it >> 16;
  const int m0 = (it & 0xffff) * BM;
  const int cnt = counts[e];
  const int rem = cnt - m0;
  const int n0 = iy * BN;

  __shared__ unsigned short sA[2][BM * BK];
  __shared__ unsigned short sB1[2][BN * BK];
  __shared__ unsigned short sB3[2][BN * BK];
  char* sA0c = (char*)sA[0]; char* sA1c = (char*)sA[1];
  char* sB10c = (char*)sB1[0]; char* sB11c = (char*)sB1[1];
  char* sB30c = (char*)sB3[0]; char* sB31c = (char*)sB3[1];

  const int tid = threadIdx.x;
  const int lane = tid & 63;
  const int wave = tid >> 6;
  const int wm = wave >> 1, wn = wave & 1;

  const int* elist = entries + e * T_TOK + m0;

  const int r0 = tid >> 3;
  const int gc = tid & 7;
  const int ra1 = r0 + 64;
  const int tok0 = elist[r0 < rem ? r0 : 0] >> 1;
  const int tok1 = elist[ra1 < rem ? ra1 : 0] >> 1;
  const unsigned short* pa0 = xb + (size_t)tok0 * H_DIM + gc * 8;
  const unsigned short* pa1 = xb + (size_t)tok1 * H_DIM + gc * 8;
  const float* pb1 = w1 + ((size_t)e * F_DIM + n0 + r0) * H_DIM + gc * 8;
  const float* pb3 = w3 + ((size_t)e * F_DIM + n0 + r0) * H_DIM + gc * 8;
  const int offA0 = LOFF(r0, gc * 16);
  const int offA1 = LOFF(ra1, gc * 16);
  const int offB = LOFF(r0, gc * 16);

  const int rowA0 = wm * 32 + (lane & 15);
  const int rowA1 = rowA0 + 16;
  const int rowB0 = wn * 32 + (lane & 15);
  const int rowB1 = rowB0 + 16;
  const int kb = (lane >> 4) * 16;

  const f32x4 zero = {0.f, 0.f, 0.f, 0.f};
  f32x4 aG[2][2], aU[2][2];
#pragma unroll
  for (int i = 0; i < 2; i++)
#pragma unroll
    for (int j = 0; j < 2; j++) { aG[i][j] = zero; aU[i][j] = zero; }

  // prologue: P = tile0, Q = tile1
  int4 Pa0 = *(const int4*)(pa0), Pa1 = *(const int4*)(pa1);
  float4 Pb10 = *(const float4*)(pb1), Pb11 = *(const float4*)(pb1 + 4);
  float4 Pb30 = *(const float4*)(pb3), Pb31 = *(const float4*)(pb3 + 4);
  int4 Qa0 = *(const int4*)(pa0 + BK), Qa1 = *(const int4*)(pa1 + BK);
  float4 Qb10 = *(const float4*)(pb1 + BK), Qb11 = *(const float4*)(pb1 + BK + 4);
  float4 Qb30 = *(const float4*)(pb3 + BK), Qb31 = *(const float4*)(pb3 + BK + 4);

  const int NT1 = H_DIM / BK;  // 32
  for (int t = 0; t < NT1; t += 2) {
    const int kp = (t + 2 < NT1) ? (t + 2) * BK : 0;
    const int kq = (t + 3 < NT1) ? (t + 3) * BK : 0;
    G1_STEP(sA0c, sB10c, sB30c, Pa0, Pa1, Pb10, Pb11, Pb30, Pb31, kp);
    G1_STEP(sA1c, sB11c, sB31c, Qa0, Qa1, Qb10, Qb11, Qb30, Qb31, kq);
  }

  // epilogue: h = silu(g)*u -> bf16 scatter by entry row
#pragma unroll
  for (int i = 0; i < 2; i++) {
#pragma unroll
    for (int r = 0; r < 4; r++) {
      const int m = wm * 32 + i * 16 + ((lane >> 4) << 2) + r;
      if (m < rem) {
        const int entry = elist[m];
        unsigned short* hp = hb + (size_t)entry * F_DIM + n0 + wn * 32 + (lane & 15);
#pragma unroll
        for (int j = 0; j < 2; j++) {
          const float g = aG[i][j][r];
          const float u = aU[i][j][r];
          const float s = g / (1.f + __expf(-g)) * u;
          hp[j * 16] = f2bf(s);
        }
      }
    }
  }
}

// ---------------- GEMM2: y = h@w2^T, weighted atomic combine ----------------
#define G2_STEP(SA, SB, VA0, VA1, B0, B1, KNEXT)                              \
  {                                                                           \
    *(int4*)((SA) + offA0) = VA0;                                             \
    *(int4*)((SA) + offA1) = VA1;                                             \
    *(int4*)((SB) + offB) = pack8(B0, B1);                                    \
    const int kn = (KNEXT);                                                   \
    VA0 = *(const int4*)(pa0 + kn);                                           \
    VA1 = *(const int4*)(pa1 + kn);                                           \
    B0 = *(const float4*)(pb + kn);                                           \
    B1 = *(const float4*)(pb + kn + 4);                                       \
    asm volatile("s_waitcnt lgkmcnt(0)" ::: "memory");                        \
    __builtin_amdgcn_s_barrier();                                             \
    _Pragma("unroll")                                                         \
    for (int kk = 0; kk < 2; kk++) {                                          \
      const int kbyte = kk * 64 + kb;                                         \
      const s16x8 a0 = *(const s16x8*)((SA) + LOFF(rowA0, kbyte));            \
      const s16x8 a1 = *(const s16x8*)((SA) + LOFF(rowA1, kbyte));            \
      const s16x8 f0 = *(const s16x8*)((SB) + LOFF(rowB0, kbyte));            \
      const s16x8 f1 = *(const s16x8*)((SB) + LOFF(rowB1, kbyte));            \
      ac[0][0] = mfma16(a0, f0, ac[0][0]); ac[0][1] = mfma16(a0, f1, ac[0][1]); \
      ac[1][0] = mfma16(a1, f0, ac[1][0]); ac[1][1] = mfma16(a1, f1, ac[1][1]); \
    }                                                                         \
  }

__global__ __launch_bounds__(512)
void moe_gemm2(const float* __restrict__ w2,
               const unsigned short* __restrict__ hb,
               const int* __restrict__ counts, const int* __restrict__ entries,
               const float* __restrict__ wlist, const int* __restrict__ items,
               float* __restrict__ out) {
  // XCD-chunked bijective swizzle: 1280 = 8 * 160
  const int lin = blockIdx.x;
  const int virt = (lin & 7) * G2_CHUNK + (lin >> 3);
  const int ix = virt % NITEM;
  const int iy = virt / NITEM;
  if (ix >= items[0]) return;
  const int it = items[1 + ix];
  const int e = it >> 16;
  const int m0 = (it & 0xffff) * BM;
  const int cnt = counts[e];
  const int rem = cnt - m0;
  const int n0 = iy * BN;

  __shared__ unsigned short sA[2][BM * BK];
  __shared__ unsigned short sB[2][BN * BK];
  char* sA0c = (char*)sA[0]; char* sA1c = (char*)sA[1];
  char* sB0c = (char*)sB[0]; char* sB1c = (char*)sB[1];

  const int tid = threadIdx.x;
  const int lane = tid & 63;
  const int wave = tid >> 6;
  const int wm = wave >> 1, wn = wave & 1;

  const int* elist = entries + e * T_TOK + m0;
  const float* wl = wlist + e * T_TOK + m0;

  const int r0 = tid >> 3;
  const int gc = tid & 7;
  const int ra1 = r0 + 64;
  const int en0 = elist[r0 < rem ? r0 : 0];
  const int en1 = elist[ra1 < rem ? ra1 : 0];
  const unsigned short* pa0 = hb + (size_t)en0 * F_DIM + gc * 8;
  const unsigned short* pa1 = hb + (size_t)en1 * F_DIM + gc * 8;
  const float* pb = w2 + ((size_t)e * H_DIM + n0 + r0) * F_DIM + gc * 8;
  const int offA0 = LOFF(r0, gc * 16);
  const int offA1 = LOFF(ra1, gc * 16);
  const int offB = LOFF(r0, gc * 16);

  const int rowA0 = wm * 32 + (lane & 15);
  const int rowA1 = rowA0 + 16;
  const int rowB0 = wn * 32 + (lane & 15);
  const int rowB1 = rowB0 + 16;
  const int kb = (lane >> 4) * 16;

  const f32x4 zero = {0.f, 0.f, 0.f, 0.f};
  f32x4 ac[2][2];
#pragma unroll
  for (int i = 0; i < 2; i++)
#pragma unroll
    for (int j = 0; j < 2; j++) ac[i][j] = zero;

  int4 Pa0 = *(const int4*)(pa0), Pa1 = *(const int4*)(pa1);
  float4 Pb0 = *(const float4*)(pb), Pb1 = *(const float4*)(pb + 4);
  int4 Qa0 = *(const int4*)(pa0 + BK), Qa1 = *(const int4*)(pa1 + BK);
  float4 Qb0 = *(const float4*)(pb + BK), Qb1 = *(const float4*)(pb + BK + 4);

  const int NT2 = F_DIM / BK;  // 22
  for (int t = 0; t < NT2; t += 2) {
    const int kp = (t + 2 < NT2) ? (t + 2) * BK : 0;
    const int kq = (t + 3 < NT2) ? (t + 3) * BK : 0;
    G2_STEP(sA0c, sB0c, Pa0, Pa1, Pb0, Pb1, kp);
    G2_STEP(sA1c, sB1c, Qa0, Qa1, Qb0, Qb1, kq);
  }

#pragma unroll
  for (int i = 0; i < 2; i++) {
#pragma unroll
    for (int r = 0; r < 4; r++) {
      const int m = wm * 32 + i * 16 + ((lane >> 4) << 2) + r;
      if (m < rem) {
        const int entry = elist[m];
        const int t = entry >> 1;
        const float wgt = wl[m];
        float* op = out + (size_t)t * H_DIM + n0 + wn * 32 + (lane & 15);
#pragma unroll
        for (int j = 0; j < 2; j++) atomicAdd(op + j * 16, wgt * ac[i][j][r]);
      }
    }
  }
}

extern "C" void kernel_launch(void* const* d_in, const int* in_sizes, int n_in,
                              void* d_out, int out_size, void* d_ws, size_t ws_size,
                              hipStream_t stream) {
  const float* x  = (const float*)d_in[0];
  const float* gw = (const float*)d_in[1];
  const float* w1 = (const float*)d_in[2];
  const float* w3 = (const float*)d_in[3];
  const float* w2 = (const float*)d_in[4];
  float* out = (float*)d_out;
  float* logits = out + (size_t)T_TOK * H_DIM;

  char* ws = (char*)d_ws;
  size_t off = 0;
  unsigned short* xb = (unsigned short*)(ws + off); off += (size_t)T_TOK * H_DIM * 2;      // 8 MB
  unsigned short* hb = (unsigned short*)(ws + off); off += (size_t)T_TOK * 2 * F_DIM * 2;  // 11.5 MB
  int*   tk_idx = (int*)(ws + off);   off += (size_t)T_TOK * 2 * 4;
  float* tk_w   = (float*)(ws + off); off += (size_t)T_TOK * 2 * 4;
  int*   counts = (int*)(ws + off);   off += 256;
  int*   entries = (int*)(ws + off);  off += (size_t)N_EXP * T_TOK * 4;
  float* wlist  = (float*)(ws + off); off += (size_t)N_EXP * T_TOK * 4;
  int*   items  = (int*)(ws + off);   off += 256;

  (void)hipMemsetAsync(d_out, 0, (size_t)out_size * sizeof(float), stream);
  router_kernel<<<dim3(T_TOK), 512, 0, stream>>>(x, gw, logits, tk_idx, tk_w, xb);
  build_lists<<<dim3(N_EXP), 64, 0, stream>>>(tk_idx, tk_w, counts, entries, wlist);
  build_items<<<dim3(1), 64, 0, stream>>>(counts, items);
  moe_gemm1<<<dim3(NITEM * G1_NY), 512, 0, stream>>>(w1, w3, xb, counts, entries, items, hb);
  moe_gemm2<<<dim3(NITEM * G2_NY), 512, 0, stream>>>(w2, hb, counts, entries, wlist, items, out);
}